// Round 9
// baseline (104.958 us; speedup 1.0000x reference)
//
#include <hip/hip_runtime.h>
#include <hip/hip_bf16.h>

// VectorQuantizer on MI355X — single-pass bf16 MFMA screening GEMM with
// 64-row waves (B fragments straight from a pre-permuted codebook into
// registers; 4 independent accumulator chains reuse each B fragment across
// 64 rows -> half the per-CU B traffic of round 7) + packed-key top-2
// trackers + wave-parallel exact fp64 resolution of banded rows.
// Phase 1 (vq_main, 128 thr = 2 waves, TILE_M=64): d' = 1+|e|^2-2(zh.eh) via
//   mfma_f32_16x16x32_bf16; tracker key = bits(d')&~31 | chunk. Rows with any
//   other code within BAND1=1e-3 recorded (winner, <=10 cands, <=2 suspect
//   trackers). Flagged rows' z re-read (L2-warm) into compact zrec[slot].
// Phase 2 (vq_fix2): exact numpy-fp32 pipeline (fp64 dot -> f32; A=fl(zn+e2);
//   d=fl(A-2t); lowest-index ties) over candidates, waves parallel, merged
//   via packed u64 (bits(d)<<32 | k). Only changed rows rewrite idx/z_q.
// d_out: z_q 8388608 f32, then indices 32768 as f32.

#define DEVI __device__ __forceinline__

typedef __attribute__((ext_vector_type(8))) short bf16x8;
typedef __attribute__((ext_vector_type(4))) float f32x4;

#define C_DIM   256
#define K_CODES 1024
#define S_DIM   8192
#define N_ROWS  32768
#define ZQ_ELEMS 8388608
#define TILE_M  64
#define NCHUNK  32
#define BAND1   1.0e-3f
#define REC_CAP 12288
#define FLT_BIG 3.402823466e+38f

// ws layout
#define WS_EFR   0                // 512KB fragment-permuted bf16 codebook
#define WS_E2F   524288
#define WS_CNT   528384
#define WS_REC   528448           // REC_CAP x 64B
#define WS_ZREC  1314880          // REC_CAP x 1KB compact z rows (optional)
#define WS_NEED  (WS_ZREC + (size_t)REC_CAP * C_DIM * 4)

DEVI unsigned short f2b(float f) {                 // fp32 -> bf16 RNE
    unsigned u = __float_as_uint(f);
    u += 0x7FFFu + ((u >> 16) & 1u);
    return (unsigned short)(u >> 16);
}
DEVI unsigned umin2(unsigned a, unsigned b) { return a < b ? a : b; }
DEVI unsigned umax2(unsigned a, unsigned b) { return a > b ? a : b; }
DEVI unsigned long long ullmin2(unsigned long long a, unsigned long long b) {
    return a < b ? a : b;
}

DEVI f32x4 MF(bf16x8 a, bf16x8 b, f32x4 c) {
    return __builtin_amdgcn_mfma_f32_16x16x32_bf16(a, b, c, 0, 0, 0);
}
DEVI bf16x8 ldsfrag(const char* L, int row, int coff) {
    const int byte = row * 512 + (coff ^ ((row & 7) << 4));
    return *reinterpret_cast<const bf16x8*>(L + byte);
}

// ---- prologue: codebook -> MFMA-fragment-permuted bf16 + exact f32 norms ----
// Fragment f (16B) of code k holds elems f*8..f*8+7. Destination:
// efrag + chunk*16384 + wn*8192 + ks*1024 + (q*16+jj)*16  (chunk=k>>5,
// wn=(k>>4)&1, jj=k&15, ks=f>>2, q=f&3). Wave loads lane*16 contiguous.
__global__ void vq_prep(const float* __restrict__ E,
                        unsigned short* __restrict__ efrag,
                        float* __restrict__ e2f, int* __restrict__ gcnt) {
    const int k = blockIdx.x;          // 1024 blocks
    const int lane = threadIdx.x;      // 64 threads, 8B (half-fragment) each
    if (k == 0 && lane == 0) *gcnt = 0;
    const float4 v = reinterpret_cast<const float4*>(E + (size_t)k * C_DIM)[lane];
    double s = (double)v.x * v.x + (double)v.y * v.y
             + (double)v.z * v.z + (double)v.w * v.w;
    ushort4 h;
    h.x = f2b(v.x); h.y = f2b(v.y); h.z = f2b(v.z); h.w = f2b(v.w);
    const int f = lane >> 1, half = lane & 1;
    const int ks = f >> 2, q = f & 3;
    const int jj = k & 15, wn = (k >> 4) & 1, chunk = k >> 5;
    char* dst = (char*)efrag + (size_t)chunk * 16384 + wn * 8192
              + ks * 1024 + (q * 16 + jj) * 16 + half * 8;
    *reinterpret_cast<ushort4*>(dst) = h;
#pragma unroll
    for (int m = 32; m; m >>= 1) s += __shfl_xor(s, m, 64);
    if (lane == 0) e2f[k] = (float)s;   // fp64-exact -> f32
}

// ---------------- phase 1 ----------------
__global__ __launch_bounds__(128) void vq_main(
        const float* __restrict__ z, const float* __restrict__ E,
        const unsigned short* __restrict__ efrag,
        const float* __restrict__ e2f,
        float* __restrict__ zrec,          // may be null
        float* __restrict__ out_zq, float* __restrict__ out_idx,
        int* __restrict__ gcnt, int* __restrict__ grec) {
    // smraw phases: A-hi stage 32KB -> key dump 64x272B -> epi [32][257] f32
    __shared__ __align__(16) char smraw[32896];
    __shared__ float e2p[1024];        // 1.0f + |e_k|^2
    __shared__ int   kfinA[64];
    __shared__ int   rowslot[64];

    const int tid = threadIdx.x;       // 0..127
    const int n0 = blockIdx.x * TILE_M;
    const int b  = n0 >> 13;
    const int s0 = n0 & (S_DIM - 1);

    {   // e2p load: 256 float4s / 128 threads
        const float4* src = reinterpret_cast<const float4*>(e2f);
#pragma unroll
        for (int i = 0; i < 2; ++i) {
            const int ix = tid + i * 128;
            const float4 v = src[ix];
            float4 w; w.x = 1.0f + v.x; w.y = 1.0f + v.y;
            w.z = 1.0f + v.z; w.w = 1.0f + v.w;
            reinterpret_cast<float4*>(e2p)[ix] = w;
        }
    }

    // ---- stage A tile (hi only): 64 z rows -> bf16, swizzled [64][512B] ----
    {
        const int s  = tid & 63;
        const int cg = tid >> 6;                        // 0..1
        const float* zb = z + (size_t)b * (C_DIM * S_DIM) + s0 + s;
#pragma unroll
        for (int ci = 0; ci < 32; ++ci) {
            const int c = cg * 4 + ci * 8;
            ushort4 h;
            h.x = f2b(zb[(size_t)(c + 0) * S_DIM]);
            h.y = f2b(zb[(size_t)(c + 1) * S_DIM]);
            h.z = f2b(zb[(size_t)(c + 2) * S_DIM]);
            h.w = f2b(zb[(size_t)(c + 3) * S_DIM]);
            const int byte = s * 512 + ((c * 2) ^ ((s & 7) << 4));
            *reinterpret_cast<ushort4*>(smraw + byte) = h;
        }
    }
    __syncthreads();

    const int wn   = tid >> 6;             // 0..1: col-half
    const int lane = tid & 63;
    const int q    = lane >> 4, jj = lane & 15;
    const int mycol = wn * 16 + jj;        // tracker/entry id 0..31

    // ---- A fragments: all 64 rows in registers (4 row-tiles x 8 ks) ----
    bf16x8 Ah[4][8];
#pragma unroll
    for (int t = 0; t < 4; ++t)
#pragma unroll
        for (int ks = 0; ks < 8; ++ks)
            Ah[t][ks] = ldsfrag(smraw, t * 16 + jj, ks * 64 + q * 16);
    __syncthreads();                       // frag reads done; smraw reusable

    // ---- main K-loop: B fragments straight from global into registers ----
    const char* gB = (const char*)efrag + wn * 8192 + (size_t)lane * 16;

#define LOADB(BR, N)                                                          \
    { _Pragma("unroll")                                                       \
      for (int ks_ = 0; ks_ < 8; ++ks_)                                       \
          BR[ks_] = *reinterpret_cast<const bf16x8*>(                         \
              gB + (size_t)(N) * 16384 + ks_ * 1024); }

#define UPD(A0, T, E2V, N)                                                    \
    { _Pragma("unroll")                                                       \
      for (int r = 0; r < 4; ++r) {                                           \
          const unsigned t_ = (__float_as_uint(                               \
              __builtin_fmaf(-2.f, A0[r], E2V)) & 0xFFFFFFE0u) | (unsigned)(N);\
          const unsigned lo_ = umin2(K1[(T)*4+r], t_);                        \
          const unsigned hi_ = umax2(K1[(T)*4+r], t_);                        \
          K1[(T)*4+r] = lo_; K2[(T)*4+r] = umin2(K2[(T)*4+r], hi_);           \
      } }

    unsigned K1[16], K2[16];
#pragma unroll
    for (int i = 0; i < 16; ++i) { K1[i] = 0xFFFFFFFFu; K2[i] = 0xFFFFFFFFu; }

    bf16x8 B0[8], B1[8];
    LOADB(B0, 0)
    LOADB(B1, 1)

#pragma unroll 1
    for (int n = 0; n < NCHUNK; n += 2) {
        {   // chunk n from B0 (4 independent acc chains over the 4 row-tiles)
            f32x4 a0 = {0.f,0.f,0.f,0.f}, a1 = a0, a2 = a0, a3 = a0;
#pragma unroll
            for (int ks = 0; ks < 8; ++ks) {
                a0 = MF(Ah[0][ks], B0[ks], a0);
                a1 = MF(Ah[1][ks], B0[ks], a1);
                a2 = MF(Ah[2][ks], B0[ks], a2);
                a3 = MF(Ah[3][ks], B0[ks], a3);
            }
            LOADB(B0, n + 2)               // n=30 -> junk read inside ws: ok
            const float e2v = e2p[n * 32 + mycol];
            UPD(a0, 0, e2v, n) UPD(a1, 1, e2v, n)
            UPD(a2, 2, e2v, n) UPD(a3, 3, e2v, n)
        }
        {   // chunk n+1 from B1
            f32x4 a0 = {0.f,0.f,0.f,0.f}, a1 = a0, a2 = a0, a3 = a0;
#pragma unroll
            for (int ks = 0; ks < 8; ++ks) {
                a0 = MF(Ah[0][ks], B1[ks], a0);
                a1 = MF(Ah[1][ks], B1[ks], a1);
                a2 = MF(Ah[2][ks], B1[ks], a2);
                a3 = MF(Ah[3][ks], B1[ks], a3);
            }
            LOADB(B1, n + 3)
            const float e2v = e2p[(n + 1) * 32 + mycol];
            UPD(a0, 0, e2v, n + 1) UPD(a1, 1, e2v, n + 1)
            UPD(a2, 2, e2v, n + 1) UPD(a3, 3, e2v, n + 1)
        }
    }

    // ---- dump per-tracker top-2 keys: [64 rows][32 entries] int2, 272B rows
#pragma unroll
    for (int t = 0; t < 4; ++t) {
#pragma unroll
        for (int r = 0; r < 4; ++r) {
            const int row = t * 16 + q * 4 + r;
            *reinterpret_cast<int2*>(smraw + row * 272 + mycol * 8) =
                make_int2((int)K1[t * 4 + r], (int)K2[t * 4 + r]);
        }
    }
    __syncthreads();

    // ---- leader: winner + banded candidate records (3 passes, no scratch) --
    if (tid < 64) {
        const char* dmp = smraw + tid * 272;
        unsigned kmin = 0xFFFFFFFFu; int emin = 0;
#pragma unroll 4
        for (int e = 0; e < 32; ++e) {
            const unsigned k1 = (unsigned)
                reinterpret_cast<const int2*>(dmp + e * 8)->x;
            if (k1 < kmin) { kmin = k1; emin = e; }
        }
        const int kmincode = (int)((kmin & 31u) << 5) | emin;
        const float dminf = __uint_as_float(kmin & 0xFFFFFFE0u);
        const unsigned limk =
            (__float_as_uint(dminf + BAND1) & 0xFFFFFFE0u) | 31u;
        int cnt = 0, nfb = 0;
#pragma unroll 4
        for (int e = 0; e < 32; ++e) {
            const int2 v = *reinterpret_cast<const int2*>(dmp + e * 8);
            if ((unsigned)v.x <= limk) {
                const int code = (int)(((unsigned)v.x & 31u) << 5) | e;
                cnt += (code != kmincode);
            }
            nfb += ((unsigned)v.y <= limk);
        }
        kfinA[tid] = kmincode;
        rowslot[tid] = -1;
        out_idx[n0 + tid] = (float)kmincode;      // provisional for flagged
        if (cnt > 0 || nfb > 0) {
            const int ov = (cnt > 10 || nfb > 2);
            const int slot = atomicAdd(gcnt, 1);
            if (slot < REC_CAP) {
                rowslot[tid] = slot;
                int* rc = grec + slot * 16;
                rc[0] = n0 + tid;
                rc[1] = ov ? -1 : (cnt | (nfb << 8));
                rc[2] = kmincode;
                if (!ov) {                 // pass 3: write cands + fb trackers
                    int ic = 0, jf = 0;
                    for (int e = 0; e < 32; ++e) {
                        const int2 v = *reinterpret_cast<const int2*>(dmp + e * 8);
                        if ((unsigned)v.x <= limk) {
                            const int code = (int)(((unsigned)v.x & 31u) << 5) | e;
                            if (code != kmincode) { rc[3 + ic] = code; ++ic; }
                        }
                        if ((unsigned)v.y <= limk) { rc[13 + jf] = e; ++jf; }
                    }
                }
            }
        }
    }
    __syncthreads();

    // ---- compact z capture for flagged rows (L2-warm strided re-read) ----
    if (zrec) {
        const size_t zb2 = (size_t)b * (C_DIM * S_DIM) + s0;
        for (int row = 0; row < 64; ++row) {
            const int slot = rowslot[row];          // LDS broadcast, uniform
            if (slot >= 0) {
                zrec[(size_t)slot * C_DIM + tid] =
                    z[zb2 + row + (size_t)tid * S_DIM];
                zrec[(size_t)slot * C_DIM + tid + 128] =
                    z[zb2 + row + (size_t)(tid + 128) * S_DIM];
            }
        }
    }

    // ---- epilogue: gather code rows in two 32-row halves via [32][257] f32
#pragma unroll
    for (int h = 0; h < 2; ++h) {
        __syncthreads();
        {
            const int slot = tid & 31;
            const int cg   = tid >> 5;         // 4 col groups of 64
            const int kk   = kfinA[h * 32 + slot];
            const float4* er = reinterpret_cast<const float4*>(
                E + (size_t)kk * C_DIM + cg * 64);
            float* lb = reinterpret_cast<float*>(smraw) + slot * 257 + cg * 64;
#pragma unroll
            for (int i = 0; i < 16; ++i) {
                const float4 v = er[i];
                lb[4 * i + 0] = v.x; lb[4 * i + 1] = v.y;
                lb[4 * i + 2] = v.z; lb[4 * i + 3] = v.w;
            }
        }
        __syncthreads();
        {
            const int sg = tid & 31;
            const int cg = tid >> 5;           // 4 col groups of 64
            float* ob = out_zq + (size_t)b * (C_DIM * S_DIM) + s0 + h * 32 + sg;
            const float* lr = reinterpret_cast<const float*>(smraw) + sg * 257;
#pragma unroll
            for (int i = 0; i < 64; ++i) {
                const int c = cg * 64 + i;
                ob[(size_t)c * S_DIM] = lr[c];
            }
        }
    }
}

// ---------------- phase 2: wave-parallel exact resolution ----------------
__global__ __launch_bounds__(256) void vq_fix2(
        const float* __restrict__ z, const float* __restrict__ E,
        const float* __restrict__ e2f, const float* __restrict__ zrec,
        const int* __restrict__ gcnt, const int* __restrict__ grec,
        float* __restrict__ out_zq, float* __restrict__ out_idx) {
    __shared__ float zsh[256];
    __shared__ double dpart[4];
    __shared__ unsigned long long wbest[4];

    const int tid = threadIdx.x;
    const int w = tid >> 6, lane = tid & 63;
    int count = gcnt[0]; if (count > REC_CAP) count = REC_CAP;

    for (int ri = blockIdx.x; ri < count; ri += gridDim.x) {
        const int* rc = grec + ri * 16;
        const int n = rc[0], flags = rc[1], kmin = rc[2];
        const int b = n >> 13, s = n & (S_DIM - 1);
        __syncthreads();                   // guard LDS reuse across rows
        const float zc = zrec ? zrec[(size_t)ri * C_DIM + tid]
                              : z[((size_t)(b * C_DIM + tid)) * S_DIM + s];
        zsh[tid] = zc;
        double p = (double)zc * (double)zc;
#pragma unroll
        for (int m = 32; m; m >>= 1) p += __shfl_xor(p, m, 64);
        if (lane == 0) dpart[w] = p;
        __syncthreads();
        const float znf = (float)((dpart[0] + dpart[1]) + (dpart[2] + dpart[3]));

        unsigned long long best = 0xFFFFFFFFFFFFFFFFull;
        if (flags >= 0) {
            const int cnt = flags & 0xFF, nfb = (flags >> 8) & 0xFF;
            const int total = 1 + cnt + 32 * nfb;
            const float4 zl4 = reinterpret_cast<const float4*>(zsh)[lane];
            for (int ci = w; ci < total; ci += 4) {    // waves independent
                int k;
                if (ci == 0) k = kmin;
                else if (ci <= cnt) k = rc[2 + ci];
                else {
                    const int t = ci - 1 - cnt;
                    k = ((t & 31) << 5) | rc[13 + (t >> 5)];
                }
                const float4 ev = reinterpret_cast<const float4*>(
                    E + (size_t)k * C_DIM)[lane];
                double dd = (double)zl4.x * ev.x + (double)zl4.y * ev.y
                          + (double)zl4.z * ev.z + (double)zl4.w * ev.w;
#pragma unroll
                for (int m = 32; m; m >>= 1) dd += __shfl_xor(dd, m, 64);
                const float t32 = (float)dd;
                const float A = znf + e2f[k];
                const float d = A - 2.0f * t32;        // > 0 always here
                best = ullmin2(best,
                    ((unsigned long long)__float_as_uint(d) << 32) | (unsigned)k);
            }
        } else {                           // ~never: per-thread 4-code full scan
            for (int j = 0; j < 4; ++j) {
                const int k = j * 256 + tid;
                const float4* er = reinterpret_cast<const float4*>(
                    E + (size_t)k * C_DIM);
                double dd = 0.0;
#pragma unroll 8
                for (int i = 0; i < 64; ++i) {
                    const float4 ev = er[i];
                    const float4 zl = reinterpret_cast<const float4*>(zsh)[i];
                    dd += (double)zl.x * ev.x + (double)zl.y * ev.y
                        + (double)zl.z * ev.z + (double)zl.w * ev.w;
                }
                const float t32 = (float)dd;
                const float d = (znf + e2f[k]) - 2.0f * t32;
                best = ullmin2(best,
                    ((unsigned long long)__float_as_uint(d) << 32) | (unsigned)k);
            }
#pragma unroll
            for (int m = 32; m; m >>= 1)
                best = ullmin2(best, (unsigned long long)__shfl_xor(
                    (long long)best, m, 64));
        }
        if (lane == 0) wbest[w] = best;
        __syncthreads();
        const unsigned long long fin =
            ullmin2(ullmin2(wbest[0], wbest[1]), ullmin2(wbest[2], wbest[3]));
        const int bk = (int)(fin & 0xFFFFFFFFull);
        if (bk != kmin) {                  // winner changed: rewrite outputs
            if (tid == 0) out_idx[n] = (float)bk;
            out_zq[((size_t)(b * C_DIM + tid)) * S_DIM + s] =
                E[(size_t)bk * C_DIM + tid];
        }
    }
}

extern "C" void kernel_launch(void* const* d_in, const int* in_sizes, int n_in,
                              void* d_out, int out_size, void* d_ws, size_t ws_size,
                              hipStream_t stream) {
    (void)in_sizes; (void)n_in; (void)out_size;
    const float* z = (const float*)d_in[0];
    const float* E = (const float*)d_in[1];
    char* wsb = (char*)d_ws;
    unsigned short* efrag = (unsigned short*)(wsb + WS_EFR); // frag-permuted
    float* e2f  = (float*)(wsb + WS_E2F);
    int*   cnt  = (int*)  (wsb + WS_CNT);
    int*   rec  = (int*)  (wsb + WS_REC);
    float* zrec = (ws_size >= WS_NEED) ? (float*)(wsb + WS_ZREC) : nullptr;
    float* out  = (float*)d_out;

    vq_prep<<<dim3(K_CODES), dim3(64), 0, stream>>>(E, efrag, e2f, cnt);
    vq_main<<<dim3(N_ROWS / TILE_M), dim3(128), 0, stream>>>(
        z, E, efrag, e2f, zrec, out, out + ZQ_ELEMS, cnt, rec);
    vq_fix2<<<dim3(2048), dim3(256), 0, stream>>>(
        z, E, e2f, zrec, cnt, rec, out, out + ZQ_ELEMS);
}

// Round 10
// 82.197 us; speedup vs baseline: 1.2769x; 1.2769x over previous
//
#include <hip/hip_runtime.h>
#include <hip/hip_bf16.h>

// VectorQuantizer on MI355X — single-pass bf16 MFMA screening GEMM (B operand
// loaded DIRECTLY into MFMA fragment registers from a pre-permuted codebook;
// no LDS staging, no barriers in the K-loop) + packed-key top-2 trackers +
// wave-parallel exact fp64 resolution of banded rows.
// Round 10 = round 7 minus the zT side-output (its 64-lane x 16B @1KB-stride
// scatter writes partial cache lines and cost ~25 us); fix2 reads flagged
// rows' z via the strided gather (L3-resident after vq_main).
// Phase 1 (vq_main): d' = 1 + |e|^2 - 2*(zh . eh) via mfma_f32_16x16x32_bf16.
//   Per-lane tracker keeps top-2 keys key = bits(d')&~31 | chunk. Rows with
//   any other code within BAND1=1e-3 of the min are recorded.
// Phase 2 (vq_fix2): per record, exact numpy-fp32 pipeline (fp64 dot -> f32;
//   A = fl(zn+e2); d = fl(A-2t); lowest-index ties); waves parallel over
//   candidates; merged via packed u64 (bits(d)<<32 | k).
// d_out: z_q 8388608 f32, then indices 32768 as f32.

#define DEVI __device__ __forceinline__

typedef __attribute__((ext_vector_type(8))) short bf16x8;
typedef __attribute__((ext_vector_type(4))) float f32x4;

#define C_DIM   256
#define K_CODES 1024
#define S_DIM   8192
#define N_ROWS  32768
#define ZQ_ELEMS 8388608
#define TILE_M  64
#define NCHUNK  32
#define BAND1   1.0e-3f
#define REC_CAP 12288
#define FLT_BIG 3.402823466e+38f

// ws layout
#define WS_EFR  0                 // 512KB fragment-permuted bf16 codebook
#define WS_E2F  524288
#define WS_CNT  528384
#define WS_REC  528448            // REC_CAP x 64B

DEVI unsigned short f2b(float f) {                 // fp32 -> bf16 RNE
    unsigned u = __float_as_uint(f);
    u += 0x7FFFu + ((u >> 16) & 1u);
    return (unsigned short)(u >> 16);
}
DEVI unsigned umin2(unsigned a, unsigned b) { return a < b ? a : b; }
DEVI unsigned umax2(unsigned a, unsigned b) { return a > b ? a : b; }
DEVI unsigned long long ullmin2(unsigned long long a, unsigned long long b) {
    return a < b ? a : b;
}

DEVI f32x4 MF(bf16x8 a, bf16x8 b, f32x4 c) {
    return __builtin_amdgcn_mfma_f32_16x16x32_bf16(a, b, c, 0, 0, 0);
}
DEVI bf16x8 ldsfrag(const char* L, int row, int coff) {
    const int byte = row * 512 + (coff ^ ((row & 7) << 4));
    return *reinterpret_cast<const bf16x8*>(L + byte);
}

// ---- prologue: codebook -> MFMA-fragment-permuted bf16 + exact f32 norms ----
// Fragment f (16B) of code k holds elems f*8..f*8+7 (contiguous bytes).
// Destination: efrag + chunk*16384 + wn*8192 + ks*1024 + (q*16+jj)*16,
// where chunk=k>>5, wn=(k>>4)&1, jj=k&15, ks=f>>2, q=f&3. A wave then loads
// its chunk-slice as lane*16 contiguous (lane = q*16+jj).
__global__ void vq_prep(const float* __restrict__ E,
                        unsigned short* __restrict__ efrag,
                        float* __restrict__ e2f, int* __restrict__ gcnt) {
    const int k = blockIdx.x;          // 1024 blocks
    const int lane = threadIdx.x;      // 64 threads, 8B (half-fragment) each
    if (k == 0 && lane == 0) *gcnt = 0;
    const float4 v = reinterpret_cast<const float4*>(E + (size_t)k * C_DIM)[lane];
    double s = (double)v.x * v.x + (double)v.y * v.y
             + (double)v.z * v.z + (double)v.w * v.w;
    ushort4 h;
    h.x = f2b(v.x); h.y = f2b(v.y); h.z = f2b(v.z); h.w = f2b(v.w);
    const int f = lane >> 1, half = lane & 1;
    const int ks = f >> 2, q = f & 3;
    const int jj = k & 15, wn = (k >> 4) & 1, chunk = k >> 5;
    char* dst = (char*)efrag + (size_t)chunk * 16384 + wn * 8192
              + ks * 1024 + (q * 16 + jj) * 16 + half * 8;
    *reinterpret_cast<ushort4*>(dst) = h;
#pragma unroll
    for (int m = 32; m; m >>= 1) s += __shfl_xor(s, m, 64);
    if (lane == 0) e2f[k] = (float)s;   // fp64-exact -> f32
}

// ---------------- phase 1 ----------------
__global__ __launch_bounds__(256, 2) void vq_main(
        const float* __restrict__ z, const float* __restrict__ E,
        const unsigned short* __restrict__ efrag,
        const float* __restrict__ e2f,
        float* __restrict__ out_zq, float* __restrict__ out_idx,
        int* __restrict__ gcnt, int* __restrict__ grec) {
    // smraw phases: A-hi stage 32KB -> key dump 17.4KB -> epi [32][257] 32.9KB
    __shared__ __align__(16) char smraw[32896];
    __shared__ float e2p[1024];        // 1.0f + |e_k|^2
    __shared__ int   kfinA[64];

    const int tid = threadIdx.x;
    const int n0 = blockIdx.x * TILE_M;
    const int b  = n0 >> 13;
    const int s0 = n0 & (S_DIM - 1);

    {   // e2p load
        const float4 v = reinterpret_cast<const float4*>(e2f)[tid];
        float4 w; w.x = 1.0f + v.x; w.y = 1.0f + v.y;
        w.z = 1.0f + v.z; w.w = 1.0f + v.w;
        reinterpret_cast<float4*>(e2p)[tid] = w;
    }

    // ---- stage A tile (hi only): z rows -> bf16, swizzled [64][512B] ----
    {
        const int s  = tid & 63;
        const int cg = tid >> 6;
        const float* zb = z + (size_t)b * (C_DIM * S_DIM) + s0 + s;
#pragma unroll
        for (int ci = 0; ci < 16; ++ci) {
            const int c = cg * 4 + ci * 16;
            ushort4 h;
            h.x = f2b(zb[(size_t)(c + 0) * S_DIM]);
            h.y = f2b(zb[(size_t)(c + 1) * S_DIM]);
            h.z = f2b(zb[(size_t)(c + 2) * S_DIM]);
            h.w = f2b(zb[(size_t)(c + 3) * S_DIM]);
            const int byte = s * 512 + ((c * 2) ^ ((s & 7) << 4));
            *reinterpret_cast<ushort4*>(smraw + byte) = h;
        }
    }
    __syncthreads();

    const int w    = tid >> 6;
    const int lane = tid & 63;
    const int wm   = w >> 1, wn = w & 1;
    const int q    = lane >> 4, jj = lane & 15;
    const int mycol = wn * 16 + jj;        // tracker/entry id 0..31

    bf16x8 Ah0[8], Ah1[8];
    {
        const int r0 = wm * 32 + jj, r1 = r0 + 16;
#pragma unroll
        for (int ks = 0; ks < 8; ++ks) {
            const int coff = ks * 64 + q * 16;
            Ah0[ks] = ldsfrag(smraw, r0, coff);
            Ah1[ks] = ldsfrag(smraw, r1, coff);
        }
    }
    // NOTE: no further barrier needed until the key dump (smraw untouched).

    // ---- main K-loop: B fragments straight from global into registers ----
    const char* gB = (const char*)efrag + (size_t)wn * 8192 + (size_t)lane * 16;

#define LOADB(BR, N)                                                          \
    { _Pragma("unroll")                                                       \
      for (int ks_ = 0; ks_ < 8; ++ks_)                                       \
          BR[ks_] = *reinterpret_cast<const bf16x8*>(                         \
              gB + (size_t)(N) * 16384 + ks_ * 1024); }

#define RCOMPUTE(BR, A0, A1)                                                  \
    { A0 = (f32x4){0.f, 0.f, 0.f, 0.f}; A1 = A0;                              \
      _Pragma("unroll")                                                       \
      for (int ks_ = 0; ks_ < 8; ++ks_) {                                     \
          A0 = MF(Ah0[ks_], BR[ks_], A0);                                     \
          A1 = MF(Ah1[ks_], BR[ks_], A1);                                     \
      } }

#define UPD(A0, A1, E2V, N)                                                   \
    { _Pragma("unroll")                                                       \
      for (int r = 0; r < 4; ++r) {                                           \
          unsigned t_ = (__float_as_uint(                                     \
              __builtin_fmaf(-2.f, A0[r], E2V)) & 0xFFFFFFE0u) | (unsigned)(N);\
          unsigned lo_ = umin2(K1[r], t_), hi_ = umax2(K1[r], t_);            \
          K1[r] = lo_; K2[r] = umin2(K2[r], hi_);                             \
          t_ = (__float_as_uint(                                              \
              __builtin_fmaf(-2.f, A1[r], E2V)) & 0xFFFFFFE0u) | (unsigned)(N);\
          lo_ = umin2(K1[4 + r], t_); hi_ = umax2(K1[4 + r], t_);             \
          K1[4 + r] = lo_; K2[4 + r] = umin2(K2[4 + r], hi_);                 \
      } }

    unsigned K1[8], K2[8];
#pragma unroll
    for (int i = 0; i < 8; ++i) { K1[i] = 0xFFFFFFFFu; K2[i] = 0xFFFFFFFFu; }

    bf16x8 Bc[8], Bn[8];
    LOADB(Bc, 0)
    LOADB(Bn, 1)
    f32x4 aA0, aA1, aB0, aB1;

#pragma unroll
    for (int p = 0; p < 16; ++p) {
        const int nA = 2 * p, nB = 2 * p + 1;
        RCOMPUTE(Bc, aA0, aA1)
        if (p < 15) LOADB(Bc, nA + 2)
        UPD(aA0, aA1, e2p[nA * 32 + mycol], nA)
        RCOMPUTE(Bn, aB0, aB1)
        if (p < 15) LOADB(Bn, nB + 2)
        UPD(aB0, aB1, e2p[nB * 32 + mycol], nB)
    }

    // ---- dump per-tracker top-2 keys: [64 rows][32 entries] int2, 272B rows
    __syncthreads();                       // A-frag reads done; smraw reusable
#pragma unroll
    for (int t = 0; t < 2; ++t) {
#pragma unroll
        for (int r = 0; r < 4; ++r) {
            const int sl = t * 4 + r;
            const int row = wm * 32 + t * 16 + q * 4 + r;
            *reinterpret_cast<int2*>(smraw + row * 272 + mycol * 8) =
                make_int2((int)K1[sl], (int)K2[sl]);
        }
    }
    __syncthreads();

    // ---- leader: winner + banded candidate records (3 passes, no scratch) --
    if (tid < 64) {
        const char* dmp = smraw + tid * 272;
        unsigned kmin = 0xFFFFFFFFu; int emin = 0;
#pragma unroll 4
        for (int e = 0; e < 32; ++e) {
            const unsigned k1 = (unsigned)
                reinterpret_cast<const int2*>(dmp + e * 8)->x;
            if (k1 < kmin) { kmin = k1; emin = e; }
        }
        const int kmincode = (int)((kmin & 31u) << 5) | emin;
        const float dminf = __uint_as_float(kmin & 0xFFFFFFE0u);
        const unsigned limk =
            (__float_as_uint(dminf + BAND1) & 0xFFFFFFE0u) | 31u;
        int cnt = 0, nfb = 0;
#pragma unroll 4
        for (int e = 0; e < 32; ++e) {
            const int2 v = *reinterpret_cast<const int2*>(dmp + e * 8);
            if ((unsigned)v.x <= limk) {
                const int code = (int)(((unsigned)v.x & 31u) << 5) | e;
                cnt += (code != kmincode);
            }
            nfb += ((unsigned)v.y <= limk);
        }
        kfinA[tid] = kmincode;
        out_idx[n0 + tid] = (float)kmincode;      // provisional for flagged
        if (cnt > 0 || nfb > 0) {
            const int ov = (cnt > 10 || nfb > 2);
            const int slot = atomicAdd(gcnt, 1);
            if (slot < REC_CAP) {
                int* rc = grec + slot * 16;
                rc[0] = n0 + tid;
                rc[1] = ov ? -1 : (cnt | (nfb << 8));
                rc[2] = kmincode;
                if (!ov) {                 // pass 3: write cands + fb trackers
                    int ic = 0, jf = 0;
                    for (int e = 0; e < 32; ++e) {
                        const int2 v = *reinterpret_cast<const int2*>(dmp + e * 8);
                        if ((unsigned)v.x <= limk) {
                            const int code = (int)(((unsigned)v.x & 31u) << 5) | e;
                            if (code != kmincode) { rc[3 + ic] = code; ++ic; }
                        }
                        if ((unsigned)v.y <= limk) { rc[13 + jf] = e; ++jf; }
                    }
                }
            }
        }
    }

    // ---- epilogue: gather code rows in two 32-row halves via [32][257] f32
#pragma unroll
    for (int h = 0; h < 2; ++h) {
        __syncthreads();
        {
            const int slot = tid & 31;
            const int cg   = tid >> 5;         // 8 col groups of 32
            const int kk   = kfinA[h * 32 + slot];
            const float4* er = reinterpret_cast<const float4*>(
                E + (size_t)kk * C_DIM + cg * 32);
            float* lb = reinterpret_cast<float*>(smraw) + slot * 257 + cg * 32;
#pragma unroll
            for (int i = 0; i < 8; ++i) {
                const float4 v = er[i];
                lb[4 * i + 0] = v.x; lb[4 * i + 1] = v.y;
                lb[4 * i + 2] = v.z; lb[4 * i + 3] = v.w;
            }
        }
        __syncthreads();
        {
            const int sg = tid & 31;
            const int cg = tid >> 5;
            float* ob = out_zq + (size_t)b * (C_DIM * S_DIM) + s0 + h * 32 + sg;
            const float* lr = reinterpret_cast<const float*>(smraw) + sg * 257;
#pragma unroll
            for (int i = 0; i < 32; ++i) {
                const int c = cg * 32 + i;
                ob[(size_t)c * S_DIM] = lr[c];
            }
        }
    }
}

// ---------------- phase 2: wave-parallel exact resolution ----------------
__global__ __launch_bounds__(256) void vq_fix2(
        const float* __restrict__ z, const float* __restrict__ E,
        const float* __restrict__ e2f,
        const int* __restrict__ gcnt, const int* __restrict__ grec,
        float* __restrict__ out_zq, float* __restrict__ out_idx) {
    __shared__ float zsh[256];
    __shared__ double dpart[4];
    __shared__ unsigned long long wbest[4];

    const int tid = threadIdx.x;
    const int w = tid >> 6, lane = tid & 63;
    int count = gcnt[0]; if (count > REC_CAP) count = REC_CAP;

    for (int ri = blockIdx.x; ri < count; ri += gridDim.x) {
        const int* rc = grec + ri * 16;
        const int n = rc[0], flags = rc[1], kmin = rc[2];
        const int b = n >> 13, s = n & (S_DIM - 1);
        __syncthreads();                   // guard LDS reuse across rows
        const float zc = z[((size_t)(b * C_DIM + tid)) * S_DIM + s]; // L3-hot
        zsh[tid] = zc;
        double p = (double)zc * (double)zc;
#pragma unroll
        for (int m = 32; m; m >>= 1) p += __shfl_xor(p, m, 64);
        if (lane == 0) dpart[w] = p;
        __syncthreads();
        const float znf = (float)((dpart[0] + dpart[1]) + (dpart[2] + dpart[3]));

        unsigned long long best = 0xFFFFFFFFFFFFFFFFull;
        if (flags >= 0) {
            const int cnt = flags & 0xFF, nfb = (flags >> 8) & 0xFF;
            const int total = 1 + cnt + 32 * nfb;
            const float4 zl4 = reinterpret_cast<const float4*>(zsh)[lane];
            for (int ci = w; ci < total; ci += 4) {    // waves independent
                int k;
                if (ci == 0) k = kmin;
                else if (ci <= cnt) k = rc[2 + ci];
                else {
                    const int t = ci - 1 - cnt;
                    k = ((t & 31) << 5) | rc[13 + (t >> 5)];
                }
                const float4 ev = reinterpret_cast<const float4*>(
                    E + (size_t)k * C_DIM)[lane];
                double dd = (double)zl4.x * ev.x + (double)zl4.y * ev.y
                          + (double)zl4.z * ev.z + (double)zl4.w * ev.w;
#pragma unroll
                for (int m = 32; m; m >>= 1) dd += __shfl_xor(dd, m, 64);
                const float t32 = (float)dd;
                const float A = znf + e2f[k];
                const float d = A - 2.0f * t32;        // > 0 always here
                best = ullmin2(best,
                    ((unsigned long long)__float_as_uint(d) << 32) | (unsigned)k);
            }
        } else {                           // ~never: per-thread 4-code full scan
            for (int j = 0; j < 4; ++j) {
                const int k = j * 256 + tid;
                const float4* er = reinterpret_cast<const float4*>(
                    E + (size_t)k * C_DIM);
                double dd = 0.0;
#pragma unroll 8
                for (int i = 0; i < 64; ++i) {
                    const float4 ev = er[i];
                    const float4 zl = reinterpret_cast<const float4*>(zsh)[i];
                    dd += (double)zl.x * ev.x + (double)zl.y * ev.y
                        + (double)zl.z * ev.z + (double)zl.w * ev.w;
                }
                const float t32 = (float)dd;
                const float d = (znf + e2f[k]) - 2.0f * t32;
                best = ullmin2(best,
                    ((unsigned long long)__float_as_uint(d) << 32) | (unsigned)k);
            }
#pragma unroll
            for (int m = 32; m; m >>= 1)
                best = ullmin2(best, (unsigned long long)__shfl_xor(
                    (long long)best, m, 64));
        }
        if (lane == 0) wbest[w] = best;
        __syncthreads();
        const unsigned long long fin =
            ullmin2(ullmin2(wbest[0], wbest[1]), ullmin2(wbest[2], wbest[3]));
        const int bk = (int)(fin & 0xFFFFFFFFull);
        if (bk != kmin) {                  // winner changed: rewrite outputs
            if (tid == 0) out_idx[n] = (float)bk;
            out_zq[((size_t)(b * C_DIM + tid)) * S_DIM + s] =
                E[(size_t)bk * C_DIM + tid];
        }
    }
}

extern "C" void kernel_launch(void* const* d_in, const int* in_sizes, int n_in,
                              void* d_out, int out_size, void* d_ws, size_t ws_size,
                              hipStream_t stream) {
    (void)in_sizes; (void)n_in; (void)out_size; (void)ws_size;
    const float* z = (const float*)d_in[0];
    const float* E = (const float*)d_in[1];
    char* wsb = (char*)d_ws;
    unsigned short* efrag = (unsigned short*)(wsb + WS_EFR); // frag-permuted
    float* e2f = (float*)(wsb + WS_E2F);
    int*   cnt = (int*)  (wsb + WS_CNT);
    int*   rec = (int*)  (wsb + WS_REC);
    float* out = (float*)d_out;

    vq_prep<<<dim3(K_CODES), dim3(64), 0, stream>>>(E, efrag, e2f, cnt);
    vq_main<<<dim3(N_ROWS / TILE_M), dim3(256), 0, stream>>>(
        z, E, efrag, e2f, out, out + ZQ_ELEMS, cnt, rec);
    vq_fix2<<<dim3(2048), dim3(256), 0, stream>>>(
        z, E, e2f, cnt, rec, out, out + ZQ_ELEMS);
}